// Round 1
// baseline (10441.421 us; speedup 1.0000x reference)
//
#include <hip/hip_runtime.h>
#include <stdint.h>

typedef _Float16 f16;
typedef _Float16 half8 __attribute__((ext_vector_type(8)));
typedef float f32x4 __attribute__((ext_vector_type(4)));

#define T_SEQ 1024
#define NWG   128
#define L0_WGS 64

// ws byte offsets
#define WS_H0  4096                   // [2][64][32][8] f16 = 65536 B
#define WS_H1  (4096 + 65536)         // [2][64][32][8] f16
#define WS_E   (4096 + 131072)        // [2][96][32][8] f16 = 98304 B

// ---- 2-level grid barrier: 16 groups x 8 wgs, monotonic epoch ----
__device__ __forceinline__ void gbar(uint32_t* ws32, int wg, uint32_t ep) {
    __syncthreads();
    if (threadIdx.x == 0) {
        __threadfence();  // release: h/e writes -> coherence point
        uint32_t* arrive = ws32 + (wg >> 3) * 32;          // 128B apart
        uint32_t old = __hip_atomic_fetch_add(arrive, 1u, __ATOMIC_RELAXED,
                                              __HIP_MEMORY_SCOPE_AGENT);
        if (old == 8u * ep - 1u) {                          // last of group
            uint32_t* root = ws32 + 512;                    // byte 2048
            uint32_t ro = __hip_atomic_fetch_add(root, 1u, __ATOMIC_RELAXED,
                                                 __HIP_MEMORY_SCOPE_AGENT);
            if (ro == 16u * ep - 1u) {                      // last group
                __threadfence();
                __hip_atomic_store(ws32 + 544, ep, __ATOMIC_RELAXED,
                                   __HIP_MEMORY_SCOPE_AGENT);  // byte 2176
            }
        }
        while (__hip_atomic_load(ws32 + 544, __ATOMIC_RELAXED,
                                 __HIP_MEMORY_SCOPE_AGENT) < ep)
            __builtin_amdgcn_s_sleep(1);
        __threadfence();  // acquire: invalidate L1/L2 before remote reads
    }
    __syncthreads();
}

__global__ void __launch_bounds__(256, 1)
lstm_fused(const int* __restrict__ x, const float* __restrict__ emb,
           const float* __restrict__ w_ih0, const float* __restrict__ w_hh0,
           const float* __restrict__ b_ih0, const float* __restrict__ b_hh0,
           const float* __restrict__ w_ih1, const float* __restrict__ w_hh1,
           const float* __restrict__ b_ih1, const float* __restrict__ b_hh1,
           const float* __restrict__ fc_w, const float* __restrict__ fc_b,
           float* __restrict__ out, uint8_t* __restrict__ ws)
{
    const int wg   = blockIdx.x;
    const int tid  = threadIdx.x;
    const int lane = tid & 63;
    const int wave = tid >> 6;
    const int mtile = wave >> 1;   // batch half (0/1)
    const int ntile = wave & 1;    // gate-row half (0/1)

    uint32_t* ws32 = (uint32_t*)ws;
    f16* h0buf = (f16*)(ws + WS_H0);   // [parity][kblk=64][b=32][8]
    f16* h1buf = (f16*)(ws + WS_H1);
    f16* ebuf  = (f16*)(ws + WS_E);    // [parity][kblk=96][b=32][8]

    const bool isL0 = (wg < L0_WGS);
    const int wloc  = isL0 ? wg : wg - L0_WGS;
    const int j0    = wloc * 8;        // owned h-columns [j0, j0+8)

    // ---------- stage weights into registers (f16 fragments) ----------
    const int r  = lane & 15;                      // row within 16-tile
    const int kg = (lane >> 4) * 8;                // k offset within 32-chunk
    const int nrow = ((ntile * 2 + (r >> 3)) << 9) + j0 + (r & 7);  // gate row

    half8 breg[40];
    if (isL0) {
#pragma unroll
        for (int kc = 0; kc < 40; ++kc) {          // K = 768 (e) + 512 (h0)
            int k = kc * 32 + kg;
            const float* src = (k < 768) ? (w_ih0 + (size_t)nrow * 768 + k)
                                         : (w_hh0 + (size_t)nrow * 512 + (k - 768));
            half8 v;
#pragma unroll
            for (int i = 0; i < 8; ++i) v[i] = (f16)src[i];
            breg[kc] = v;
        }
    } else {
#pragma unroll
        for (int kc = 0; kc < 32; ++kc) {          // K = 512 (h0) + 512 (h1)
            int k = kc * 32 + kg;
            const float* src = (k < 512) ? (w_ih1 + (size_t)nrow * 512 + k)
                                         : (w_hh1 + (size_t)nrow * 512 + (k - 512));
            half8 v;
#pragma unroll
            for (int i = 0; i < 8; ++i) v[i] = (f16)src[i];
            breg[kc] = v;
        }
    }

    __shared__ float accs[32][33];   // [batch][gate-col], +1 pad
    __shared__ float bias_lds[32];
    if (tid < 32) {
        int n2 = ((tid >> 3) << 9) + j0 + (tid & 7);
        bias_lds[tid] = isL0 ? (b_ih0[n2] + b_hh0[n2]) : (b_ih1[n2] + b_hh1[n2]);
    }

    // ---------- init: zero h0/h1 parity-1 planes; convert e_0 ----------
    {
        int idx = wg * 256 + tid;                  // 0..32767
        if (idx < 16384) h0buf[16384 + idx] = (f16)0.f;
        else             h1buf[16384 + (idx - 16384)] = (f16)0.f;
    }
    if (tid < 192) {
        int el = wg * 192 + tid;                   // 0..24575
        int b = el / 768, k = el % 768;
        int tok = x[b * T_SEQ + 0];
        ebuf[((size_t)(k >> 3) * 32 + b) * 8 + (k & 7)] = (f16)emb[(size_t)tok * 768 + k];
    }
    gbar(ws32, wg, 1u);

    float cst = 0.f;                                // c-state for (tb, j0+tj)
    const int tb = tid >> 3, tj = tid & 7;
    const int arow = mtile * 16 + r;
    const int kgb  = lane >> 4;

    for (int s = 0; s <= T_SEQ; ++s) {
        const bool active = isL0 ? (s < T_SEQ) : (s >= 1);
        if (active) {
            f32x4 acc0 = {0.f, 0.f, 0.f, 0.f}, acc1 = {0.f, 0.f, 0.f, 0.f};
            if (isL0) {
                const f16* pe = ebuf  + (size_t)(s & 1) * 24576;        // e_s
                const f16* ph = h0buf + (size_t)((s + 1) & 1) * 16384;  // h0_{s-1}
#pragma unroll
                for (int kc = 0; kc < 24; ++kc) {
                    const half8 a = *(const half8*)(pe + (((size_t)(kc * 4 + kgb) * 32 + arow) << 3));
                    if (kc & 1) acc1 = __builtin_amdgcn_mfma_f32_16x16x32_f16(a, breg[kc], acc1, 0, 0, 0);
                    else        acc0 = __builtin_amdgcn_mfma_f32_16x16x32_f16(a, breg[kc], acc0, 0, 0, 0);
                }
#pragma unroll
                for (int kc = 24; kc < 40; ++kc) {
                    const half8 a = *(const half8*)(ph + (((size_t)((kc - 24) * 4 + kgb) * 32 + arow) << 3));
                    if (kc & 1) acc1 = __builtin_amdgcn_mfma_f32_16x16x32_f16(a, breg[kc], acc1, 0, 0, 0);
                    else        acc0 = __builtin_amdgcn_mfma_f32_16x16x32_f16(a, breg[kc], acc0, 0, 0, 0);
                }
            } else {
                const f16* pa = h0buf + (size_t)((s + 1) & 1) * 16384;  // h0_{s-1}
                const f16* pb = h1buf + (size_t)(s & 1) * 16384;        // h1_{s-2}
#pragma unroll
                for (int kc = 0; kc < 16; ++kc) {
                    const half8 a = *(const half8*)(pa + (((size_t)(kc * 4 + kgb) * 32 + arow) << 3));
                    if (kc & 1) acc1 = __builtin_amdgcn_mfma_f32_16x16x32_f16(a, breg[kc], acc1, 0, 0, 0);
                    else        acc0 = __builtin_amdgcn_mfma_f32_16x16x32_f16(a, breg[kc], acc0, 0, 0, 0);
                }
#pragma unroll
                for (int kc = 16; kc < 32; ++kc) {
                    const half8 a = *(const half8*)(pb + (((size_t)((kc - 16) * 4 + kgb) * 32 + arow) << 3));
                    if (kc & 1) acc1 = __builtin_amdgcn_mfma_f32_16x16x32_f16(a, breg[kc], acc1, 0, 0, 0);
                    else        acc0 = __builtin_amdgcn_mfma_f32_16x16x32_f16(a, breg[kc], acc0, 0, 0, 0);
                }
            }
            f32x4 accv = acc0 + acc1;
            const int crow0 = mtile * 16 + (lane >> 4) * 4;   // D: row=(lane>>4)*4+reg
            const int ccol  = ntile * 16 + r;                 //    col=lane&15
#pragma unroll
            for (int q = 0; q < 4; ++q) accs[crow0 + q][ccol] = accv[q];
        }
        __syncthreads();
        if (active) {
            float gi = accs[tb][tj]      + bias_lds[tj];
            float gf = accs[tb][8 + tj]  + bias_lds[8 + tj];
            float gg = accs[tb][16 + tj] + bias_lds[16 + tj];
            float go = accs[tb][24 + tj] + bias_lds[24 + tj];
            float si = __builtin_amdgcn_rcpf(1.f + __expf(-gi));
            float sf = __builtin_amdgcn_rcpf(1.f + __expf(-gf));
            float so = __builtin_amdgcn_rcpf(1.f + __expf(-go));
            float tg = 1.f - 2.f * __builtin_amdgcn_rcpf(__expf(2.f * gg) + 1.f);
            cst = sf * cst + si * tg;
            float hv = so * (1.f - 2.f * __builtin_amdgcn_rcpf(__expf(2.f * cst) + 1.f));
            int j = j0 + tj;
            f16* dst = isL0 ? (h0buf + (size_t)(s & 1) * 16384)          // h0_s
                            : (h1buf + (size_t)((s + 1) & 1) * 16384);   // h1_{s-1}
            dst[((size_t)(j >> 3) * 32 + tb) * 8 + (j & 7)] = (f16)hv;
        }
        // convert embeddings for step s+1 (all wgs share the work)
        if (s + 1 < T_SEQ && tid < 192) {
            int el = wg * 192 + tid;
            int b = el / 768, k = el % 768;
            int tok = x[b * T_SEQ + (s + 1)];
            ebuf[(size_t)((s + 1) & 1) * 24576 + ((size_t)(k >> 3) * 32 + b) * 8 + (k & 7)] =
                (f16)emb[(size_t)tok * 768 + k];
        }
        gbar(ws32, wg, (uint32_t)(s + 2));
    }

    // ---------- FC epilogue: h2 = h1_{1023} (parity 1) ----------
    if (wg == 0 && tid < 160) {
        int b = tid / 5, n = tid % 5;
        const f16* h2 = h1buf + 16384;
        float fsum = fc_b[n];
#pragma unroll 8
        for (int j = 0; j < 512; ++j)
            fsum += (float)h2[((size_t)(j >> 3) * 32 + b) * 8 + (j & 7)] * fc_w[n * 512 + j];
        out[b * 5 + n] = fsum;
    }
}

extern "C" void kernel_launch(void* const* d_in, const int* in_sizes, int n_in,
                              void* d_out, int out_size, void* d_ws, size_t ws_size,
                              hipStream_t stream) {
    (void)in_sizes; (void)n_in; (void)out_size; (void)ws_size;
    // barrier counters/flag must be zero each call (graph-capture safe)
    hipMemsetAsync(d_ws, 0, 4096, stream);
    lstm_fused<<<dim3(NWG), dim3(256), 0, stream>>>(
        (const int*)d_in[0],  (const float*)d_in[1],
        (const float*)d_in[2], (const float*)d_in[3],
        (const float*)d_in[4], (const float*)d_in[5],
        (const float*)d_in[6], (const float*)d_in[7],
        (const float*)d_in[8], (const float*)d_in[9],
        (const float*)d_in[10], (const float*)d_in[11],
        (float*)d_out, (uint8_t*)d_ws);
}

// Round 2
// 7245.366 us; speedup vs baseline: 1.4411x; 1.4411x over previous
//
#include <hip/hip_runtime.h>
#include <stdint.h>

typedef _Float16 f16;
typedef _Float16 half8 __attribute__((ext_vector_type(8)));
typedef _Float16 half4 __attribute__((ext_vector_type(4)));
typedef float f32x4 __attribute__((ext_vector_type(4)));
typedef unsigned long long u64;

#define T_SEQ 1024
#define NWG   128
#define L0_WGS 64

// ws byte offsets (ws32[0..127] = arrive slots, memset to 0 each launch)
#define WS_H0  4096                   // [2 parity][512/8 kblk][32 b][8] f16 = 65536 B
#define WS_H1  (4096 + 65536)

__device__ __forceinline__ half8 ld_h8(f16* p) {
    u64 lo = __hip_atomic_load((u64*)p,     __ATOMIC_RELAXED, __HIP_MEMORY_SCOPE_AGENT);
    u64 hi = __hip_atomic_load((u64*)p + 1, __ATOMIC_RELAXED, __HIP_MEMORY_SCOPE_AGENT);
    union { u64 q[2]; half8 v; } u;
    u.q[0] = lo; u.q[1] = hi;
    return u.v;
}

__global__ void __launch_bounds__(256, 1)
lstm_fused(const int* __restrict__ x, const float* __restrict__ emb,
           const float* __restrict__ w_ih0, const float* __restrict__ w_hh0,
           const float* __restrict__ b_ih0, const float* __restrict__ b_hh0,
           const float* __restrict__ w_ih1, const float* __restrict__ w_hh1,
           const float* __restrict__ b_ih1, const float* __restrict__ b_hh1,
           const float* __restrict__ fc_w, const float* __restrict__ fc_b,
           float* __restrict__ out, uint8_t* __restrict__ ws)
{
    const int wg   = blockIdx.x;
    const int tid  = threadIdx.x;
    const int lane = tid & 63;
    const int wave = tid >> 6;
    const int mtile = wave >> 1;   // batch half (0/1)
    const int ntile = wave & 1;    // gate-row half (0/1)

    uint32_t* ws32 = (uint32_t*)ws;            // arrive[0..127]
    f16* h0buf = (f16*)(ws + WS_H0);
    f16* h1buf = (f16*)(ws + WS_H1);

    const bool isL0 = (wg < L0_WGS);
    const int wloc  = isL0 ? wg : wg - L0_WGS;
    const int j0    = wloc * 8;                // owned h-columns [j0, j0+8)

    // ---- LDS: e double-buffer (L0 only uses it) + epilogue scratch ----
    __shared__ f16   elds[2 * 24576];          // [par][kblk=96][b=32][8] = 96 KB
    __shared__ float accs[32][33];
    __shared__ float bias_lds[32];
    __shared__ f16   hsh[32][8];

    // ---------- stage weights into registers (f16 fragments) ----------
    const int r  = lane & 15;
    const int kg = (lane >> 4) * 8;
    const int nrow = ((ntile * 2 + (r >> 3)) << 9) + j0 + (r & 7);

    half8 breg[40];
    if (isL0) {
#pragma unroll
        for (int kc = 0; kc < 40; ++kc) {      // K = 768 (e) + 512 (h0)
            int k = kc * 32 + kg;
            const float* src = (k < 768) ? (w_ih0 + (size_t)nrow * 768 + k)
                                         : (w_hh0 + (size_t)nrow * 512 + (k - 768));
            half8 v;
#pragma unroll
            for (int i = 0; i < 8; ++i) v[i] = (f16)src[i];
            breg[kc] = v;
        }
    } else {
#pragma unroll
        for (int kc = 0; kc < 32; ++kc) {      // K = 512 (h0) + 512 (h1)
            int k = kc * 32 + kg;
            const float* src = (k < 512) ? (w_ih1 + (size_t)nrow * 512 + k)
                                         : (w_hh1 + (size_t)nrow * 512 + (k - 512));
            half8 v;
#pragma unroll
            for (int i = 0; i < 8; ++i) v[i] = (f16)src[i];
            breg[kc] = v;
        }
    }

    if (tid < 32) {
        int n2 = ((tid >> 3) << 9) + j0 + (tid & 7);
        bias_lds[tid] = isL0 ? (b_ih0[n2] + b_hh0[n2]) : (b_ih1[n2] + b_hh1[n2]);
    }

    // ---------- zero h0/h1 parity-1 planes (atomic write-through) ----------
    {
        int gid = wg * 256 + tid;              // need 8192 u64 stores
        if (gid < 8192) {
            u64* base = (gid < 4096) ? (u64*)(h0buf + 16384) : (u64*)(h1buf + 16384);
            __hip_atomic_store(base + (gid & 4095), 0ULL,
                               __ATOMIC_RELAXED, __HIP_MEMORY_SCOPE_AGENT);
        }
    }

    // ---------- e_0 into elds[0] (each L0 wg converts its own copy) ----------
    if (isL0) {
        int b = tid >> 3, k0 = (tid & 7) * 96;
        int tok = x[b * T_SEQ + 0];
        const float* src = emb + (size_t)tok * 768;
#pragma unroll
        for (int kk = 0; kk < 96; kk += 4) {
            int k = k0 + kk;
            float4 v = *(const float4*)(src + k);
            half4 h; h[0] = (f16)v.x; h[1] = (f16)v.y; h[2] = (f16)v.z; h[3] = (f16)v.w;
            *(half4*)&elds[((k >> 3) * 32 + b) * 8 + (k & 7)] = h;
        }
    }

    // ---------- barrier ep=1 (init visible) ----------
    __syncthreads();
    if (tid == 0) {
        asm volatile("s_waitcnt vmcnt(0)" ::: "memory");
        __hip_atomic_store(ws32 + wg, 1u, __ATOMIC_RELAXED, __HIP_MEMORY_SCOPE_AGENT);
    }
    if (tid < 128) {
        while (__hip_atomic_load(ws32 + tid, __ATOMIC_RELAXED, __HIP_MEMORY_SCOPE_AGENT) < 1u)
            __builtin_amdgcn_s_sleep(2);
    }
    __syncthreads();

    float cst = 0.f;
    const int tb = tid >> 3, tj = tid & 7;
    const int arow = mtile * 16 + r;
    const int kgb  = lane >> 4;

    for (int s = 0; s <= T_SEQ; ++s) {
        const bool active = isL0 ? (s < T_SEQ) : (s >= 1);
        if (active) {
            f32x4 acc0 = {0.f, 0.f, 0.f, 0.f}, acc1 = {0.f, 0.f, 0.f, 0.f};
            if (isL0) {
                const f16* pe = elds + (s & 1) * 24576;                 // e_s (LDS)
                f16* ph = h0buf + (size_t)((s + 1) & 1) * 16384;        // h0_{s-1}
#pragma unroll
                for (int kc = 0; kc < 24; ++kc) {
                    const half8 a = *(const half8*)(pe + (((kc * 4 + kgb) * 32 + arow) << 3));
                    if (kc & 1) acc1 = __builtin_amdgcn_mfma_f32_16x16x32_f16(a, breg[kc], acc1, 0, 0, 0);
                    else        acc0 = __builtin_amdgcn_mfma_f32_16x16x32_f16(a, breg[kc], acc0, 0, 0, 0);
                }
#pragma unroll
                for (int kc = 24; kc < 40; ++kc) {
                    const half8 a = ld_h8(ph + ((((kc - 24) * 4 + kgb) * 32 + arow) << 3));
                    if (kc & 1) acc1 = __builtin_amdgcn_mfma_f32_16x16x32_f16(a, breg[kc], acc1, 0, 0, 0);
                    else        acc0 = __builtin_amdgcn_mfma_f32_16x16x32_f16(a, breg[kc], acc0, 0, 0, 0);
                }
            } else {
                f16* pa = h0buf + (size_t)((s + 1) & 1) * 16384;        // h0_{s-1}
                f16* pb = h1buf + (size_t)(s & 1) * 16384;              // h1_{s-2}
#pragma unroll
                for (int kc = 0; kc < 16; ++kc) {
                    const half8 a = ld_h8(pa + (((kc * 4 + kgb) * 32 + arow) << 3));
                    if (kc & 1) acc1 = __builtin_amdgcn_mfma_f32_16x16x32_f16(a, breg[kc], acc1, 0, 0, 0);
                    else        acc0 = __builtin_amdgcn_mfma_f32_16x16x32_f16(a, breg[kc], acc0, 0, 0, 0);
                }
#pragma unroll
                for (int kc = 16; kc < 32; ++kc) {
                    const half8 a = ld_h8(pb + ((((kc - 16) * 4 + kgb) * 32 + arow) << 3));
                    if (kc & 1) acc1 = __builtin_amdgcn_mfma_f32_16x16x32_f16(a, breg[kc], acc1, 0, 0, 0);
                    else        acc0 = __builtin_amdgcn_mfma_f32_16x16x32_f16(a, breg[kc], acc0, 0, 0, 0);
                }
            }
            f32x4 accv = acc0 + acc1;
            const int crow0 = mtile * 16 + (lane >> 4) * 4;   // C/D: row=(lane>>4)*4+reg
            const int ccol  = ntile * 16 + r;                 //      col=lane&15
#pragma unroll
            for (int q = 0; q < 4; ++q) accs[crow0 + q][ccol] = accv[q];
        }
        __syncthreads();
        if (active) {
            float gi = accs[tb][tj]      + bias_lds[tj];
            float gf = accs[tb][8 + tj]  + bias_lds[8 + tj];
            float gg = accs[tb][16 + tj] + bias_lds[16 + tj];
            float go = accs[tb][24 + tj] + bias_lds[24 + tj];
            float si = __builtin_amdgcn_rcpf(1.f + __expf(-gi));
            float sf = __builtin_amdgcn_rcpf(1.f + __expf(-gf));
            float so = __builtin_amdgcn_rcpf(1.f + __expf(-go));
            float tg = 1.f - 2.f * __builtin_amdgcn_rcpf(__expf(2.f * gg) + 1.f);
            cst = sf * cst + si * tg;
            float hv = so * (1.f - 2.f * __builtin_amdgcn_rcpf(__expf(2.f * cst) + 1.f));
            hsh[tb][tj] = (f16)hv;
        }
        __syncthreads();                       // hsh ready (wave 0 reads rows 0..31)
        if (active && tid < 32) {              // pack 8 f16 = 16B per batch row
            u64* dst = (u64*)(isL0 ? (h0buf + (size_t)(s & 1) * 16384)
                                   : (h1buf + (size_t)((s + 1) & 1) * 16384))
                       + ((size_t)wloc * 32 + tid) * 2;
            const u64* srcp = (const u64*)hsh + tid * 2;
            u64 q0 = srcp[0], q1 = srcp[1];
            __hip_atomic_store(dst,     q0, __ATOMIC_RELAXED, __HIP_MEMORY_SCOPE_AGENT);
            __hip_atomic_store(dst + 1, q1, __ATOMIC_RELAXED, __HIP_MEMORY_SCOPE_AGENT);
        }
        if (tid == 0) {                        // release: drain wave-0 stores, signal
            asm volatile("s_waitcnt vmcnt(0)" ::: "memory");
            __hip_atomic_store(ws32 + wg, (uint32_t)(s + 2),
                               __ATOMIC_RELAXED, __HIP_MEMORY_SCOPE_AGENT);
        }
        // ---- hidden under barrier wait: convert e_{s+1} into other parity ----
        if (isL0 && (s + 1 < T_SEQ)) {
            f16* edst = elds + ((s + 1) & 1) * 24576;
            int b = tid >> 3, k0 = (tid & 7) * 96;
            int tok = x[b * T_SEQ + (s + 1)];
            const float* src = emb + (size_t)tok * 768;
#pragma unroll
            for (int kk = 0; kk < 96; kk += 4) {
                int k = k0 + kk;
                float4 v = *(const float4*)(src + k);
                half4 h; h[0] = (f16)v.x; h[1] = (f16)v.y; h[2] = (f16)v.z; h[3] = (f16)v.w;
                *(half4*)&edst[((k >> 3) * 32 + b) * 8 + (k & 7)] = h;
            }
        }
        __builtin_amdgcn_sched_barrier(0);     // keep e-convert above the poll
        if (tid < 128) {
            const uint32_t ep = (uint32_t)(s + 2);
            while (__hip_atomic_load(ws32 + tid, __ATOMIC_RELAXED, __HIP_MEMORY_SCOPE_AGENT) < ep)
                __builtin_amdgcn_s_sleep(2);
        }
        __syncthreads();
    }

    // ---------- FC epilogue: h2 = h1_{1023} (parity 1) ----------
    if (wg == 0) {
        u64* h2g = (u64*)(h1buf + 16384);
        u64* stg = (u64*)elds;                 // reuse LDS as staging (4096 u64)
        for (int i = tid; i < 4096; i += 256)
            stg[i] = __hip_atomic_load(h2g + i, __ATOMIC_RELAXED, __HIP_MEMORY_SCOPE_AGENT);
        __syncthreads();
        if (tid < 160) {
            int b = tid / 5, n = tid % 5;
            const f16* h2 = (const f16*)stg;
            float fsum = fc_b[n];
#pragma unroll 8
            for (int j = 0; j < 512; ++j)
                fsum += (float)h2[((j >> 3) * 32 + b) * 8 + (j & 7)] * fc_w[n * 512 + j];
            out[b * 5 + n] = fsum;
        }
    }
}

extern "C" void kernel_launch(void* const* d_in, const int* in_sizes, int n_in,
                              void* d_out, int out_size, void* d_ws, size_t ws_size,
                              hipStream_t stream) {
    (void)in_sizes; (void)n_in; (void)out_size; (void)ws_size;
    hipMemsetAsync(d_ws, 0, 4096, stream);     // arrive slots must start at 0
    lstm_fused<<<dim3(NWG), dim3(256), 0, stream>>>(
        (const int*)d_in[0],  (const float*)d_in[1],
        (const float*)d_in[2], (const float*)d_in[3],
        (const float*)d_in[4], (const float*)d_in[5],
        (const float*)d_in[6], (const float*)d_in[7],
        (const float*)d_in[8], (const float*)d_in[9],
        (const float*)d_in[10], (const float*)d_in[11],
        (float*)d_out, (uint8_t*)d_ws);
}